// Round 9
// baseline (86.895 us; speedup 1.0000x reference)
//
#include <hip/hip_runtime.h>
#include <hip/hip_bf16.h>

// SubjectSpecificProjection: per-subject 2-layer MLP (256->512->512) + L2 normalize.
// R9: SMALL-BLOCK CONCURRENCY. R6-R8 data fits a per-BLOCK fetch rate (~28 GB/s
//     packed) that scales with co-resident blocks/CU. So: 256-thr/4-wave blocks,
//     LDS <20KB, VGPR<=128 -> 4-8 resident blocks/CU. gemm1 = chunk128 x panel128
//     (564 blk @192KB). gemm2 = chunk64 x panel256 (538 blk @320KB) with
//     cross-block norm combine: post partial sq -> flag -> spin for partner
//     (adjacent pair ids; deterministic fixed-order sum; flags zeroed per call).

#define BATCH 16384
#define EEG 256
#define CLIP 512
#define NSUB 13

// meta layout (ints):
#define M_BCNT 0        // [64][13]
#define M_SOFF 832      // [14] sample offsets per subject
#define M_TOT  846      // [13]
#define M_C128 859      // [14] 128-row chunk offsets
#define M_C64  873      // [14] 64-row chunk offsets
#define M_IDX  896      // [16384]
#define M_END  17280

typedef unsigned short u16;
typedef __attribute__((ext_vector_type(8))) short short8;
typedef __attribute__((ext_vector_type(4))) float f32x4;

__device__ __forceinline__ u16 f2bf(float f) {
    union { float f; unsigned int u; } v; v.f = f;
    unsigned int u = v.u;
    unsigned int r = (u + 0x7FFFu + ((u >> 16) & 1u)) >> 16;   // RNE
    return (u16)r;
}

// ---- weight convert + pack (R7 layout) + fused histogram ----
// chunk(s,g,t) = 2048 u16 [slot(4)][colin(64)][e(8)]; element =
//   W[s][k = t*32 + slot*8 + e][n = g*64 + colin].
__global__ __launch_bounds__(256) void convert_pack(
    const float* __restrict__ W1, const float* __restrict__ W2,
    u16* __restrict__ w1p, u16* __restrict__ w2p,
    const int* __restrict__ sid, int* __restrict__ meta) {
    __shared__ u16 T[64][72];
    __shared__ int hh[NSUB];
    int b = blockIdx.x;
    const float* src; u16* dstbase; int ksteps;
    int s, kt, g;
    if (b < 416) {                     // W1: 13 x (4 kt)x(8 g)
        s = b >> 5; int t = b & 31;
        kt = t >> 3; g = t & 7;
        ksteps = 8;
        src = W1 + (size_t)s * EEG * CLIP;
        dstbase = w1p + (size_t)s * CLIP * EEG;
    } else {                           // W2: 13 x (8 kt)x(8 g)
        b -= 416; s = b >> 6; int t = b & 63;
        kt = t >> 3; g = t & 7;
        ksteps = 16;
        src = W2 + (size_t)s * CLIP * CLIP;
        dstbase = w2p + (size_t)s * CLIP * CLIP;
    }
    int k0 = kt << 6, n0 = g << 6;
    int tid = threadIdx.x;
    int rk = tid >> 2;
    int cg = (tid & 3) << 4;
    const float4* p4 = reinterpret_cast<const float4*>(src + (size_t)(k0 + rk) * CLIP + n0 + cg);
    #pragma unroll
    for (int jj = 0; jj < 4; ++jj) {
        float4 v = p4[jj];
        T[cg + jj * 4 + 0][rk] = f2bf(v.x);
        T[cg + jj * 4 + 1][rk] = f2bf(v.y);
        T[cg + jj * 4 + 2][rk] = f2bf(v.z);
        T[cg + jj * 4 + 3][rk] = f2bf(v.w);
    }
    __syncthreads();
    int colin = tid & 63, sl = (tid >> 6) & 3;
    #pragma unroll
    for (int half = 0; half < 2; ++half) {
        int t = kt * 2 + half;
        u16* dst = dstbase + ((size_t)(g * ksteps + t)) * 2048 + sl * 512 + colin * 8;
        *reinterpret_cast<short8*>(dst) =
            *reinterpret_cast<const short8*>(&T[colin][half * 32 + sl * 8]);
    }
    if (blockIdx.x < 64) {             // fused histogram
        if (tid < NSUB) hh[tid] = 0;
        __syncthreads();
        atomicAdd(&hh[sid[blockIdx.x * 256 + tid]], 1);
        __syncthreads();
        if (tid < NSUB) meta[M_BCNT + blockIdx.x * NSUB + tid] = hh[tid];
    }
}

// ---- scan + scatter + flag-zero in one kernel ----
__global__ __launch_bounds__(256) void scanscatter_k(
    const int* __restrict__ sid, int* __restrict__ meta, int* __restrict__ flags) {
    __shared__ int cnt[64][NSUB];
    __shared__ int so[NSUB + 1], myoff[NSUB], tot[NSUB];
    __shared__ int h[NSUB];
    int tid = threadIdx.x;
    // zero pair flags (512 slots) - must precede gemm2 (stream-ordered)
    if (blockIdx.x == 0) { flags[tid] = 0; flags[tid + 256] = 0; }
    for (int i = tid; i < 64 * NSUB; i += 256)
        cnt[i / NSUB][i % NSUB] = meta[M_BCNT + i];
    if (tid < NSUB) h[tid] = 0;
    __syncthreads();
    if (tid < NSUB) {
        int run = 0, mine = 0;
        for (int b = 0; b < 64; ++b) {
            if (b == (int)blockIdx.x) mine = run;
            run += cnt[b][tid];
        }
        tot[tid] = run; myoff[tid] = mine;
    }
    __syncthreads();
    if (tid == 0) {
        int off = 0;
        for (int s = 0; s < NSUB; ++s) { so[s] = off; off += tot[s]; }
        so[NSUB] = off;
    }
    __syncthreads();
    if (blockIdx.x == 0) {
        if (tid < NSUB + 1) meta[M_SOFF + tid] = so[tid];
        if (tid < NSUB) meta[M_TOT + tid] = tot[tid];
        if (tid == 0) {
            int c128 = 0, c64 = 0;
            for (int s = 0; s < NSUB; ++s) {
                meta[M_C128 + s] = c128; meta[M_C64 + s] = c64;
                c128 += (tot[s] + 127) >> 7;
                c64  += (tot[s] + 63) >> 6;
            }
            meta[M_C128 + NSUB] = c128;
            meta[M_C64 + NSUB] = c64;
        }
    }
    int i = blockIdx.x * 256 + tid;
    int s = sid[i];
    int r = atomicAdd(&h[s], 1);
    meta[M_IDX + so[s] + myoff[s] + r] = i;
}

// ---- K1: H = relu(X @ W1 + b1). chunk=128 rows x panel=128 cols, 256 thr ----
__global__ __launch_bounds__(256) void gemm1_k(
    const float* __restrict__ X, const float* __restrict__ b1,
    const u16* __restrict__ w1p, const int* __restrict__ meta,
    u16* __restrict__ H) {

    __shared__ u16 Xc[128 * 72];       // 18.4 KB
    __shared__ int info[4];
    __shared__ int rowidx[128];
    __shared__ int cobuf[14], sobuf[14], totbuf[NSUB];

    int tid = threadIdx.x;

    int nwg = gridDim.x;
    int q = nwg >> 3, r = nwg & 7;
    int xcd = blockIdx.x & 7, idx = blockIdx.x >> 3;
    int bid = (xcd < r) ? xcd * (q + 1) + idx : r * (q + 1) + (xcd - r) * q + idx;
    int chunk = bid >> 2, panel = bid & 3;     // panel-sibs adjacent -> same XCD

    if (tid < 14) { cobuf[tid] = meta[M_C128 + tid]; sobuf[tid] = meta[M_SOFF + tid]; }
    if (tid < NSUB) totbuf[tid] = meta[M_TOT + tid];
    __syncthreads();
    if (tid == 0) {
        int total = cobuf[NSUB];
        if (chunk < total) {
            int s = 0;
            while (s < NSUB && !(chunk >= cobuf[s] && chunk < cobuf[s + 1])) s++;
            int ch = chunk - cobuf[s];
            info[0] = s;
            info[1] = sobuf[s] + ch * 128;
            info[2] = min(128, totbuf[s] - ch * 128);
        } else info[0] = -1;
    }
    __syncthreads();
    if (info[0] < 0) return;
    int s = info[0], rowbase = info[1], nrows = info[2];
    if (tid < 128) rowidx[tid] = meta[M_IDX + rowbase + min(tid, nrows - 1)];

    int wave = tid >> 6, lane = tid & 63;
    int c = lane & 15, gl = lane >> 4;
    int wm = wave >> 1, wn = wave & 1;         // 2M x 2N waves
    int col0 = panel * 128 + wn * 64;
    const u16* w1c = w1p + (size_t)s * CLIP * EEG + (size_t)(col0 >> 6) * 8 * 2048;

    f32x4 acc[4][4];
    #pragma unroll
    for (int mi = 0; mi < 4; ++mi)
        #pragma unroll
        for (int ni = 0; ni < 4; ++ni)
            acc[mi][ni] = (f32x4){0.f, 0.f, 0.f, 0.f};

    int srow = tid >> 1, half = tid & 1;       // 128 rows, 2 thr/row, 8 float4 each

    for (int kc = 0; kc < 4; ++kc) {
        __syncthreads();
        {   // stage 128x64 X chunk, fp32 -> bf16
            const float4* xp = reinterpret_cast<const float4*>(
                X + (size_t)rowidx[srow] * EEG) + kc * 16 + half * 8;
            u16* xd = &Xc[srow * 72 + half * 32];
            #pragma unroll
            for (int j = 0; j < 8; ++j) {
                float4 v = xp[j];
                union { u16 u[4]; uint2 qq; } pk;
                pk.u[0] = f2bf(v.x); pk.u[1] = f2bf(v.y);
                pk.u[2] = f2bf(v.z); pk.u[3] = f2bf(v.w);
                *reinterpret_cast<uint2*>(&xd[j * 4]) = pk.qq;
            }
        }
        __syncthreads();
        #pragma unroll
        for (int k0 = 0; k0 < 64; k0 += 32) {
            int t = kc * 2 + (k0 >> 5);
            short8 a[4], bb[4];
            #pragma unroll
            for (int ni = 0; ni < 4; ++ni)
                bb[ni] = *reinterpret_cast<const short8*>(
                    &w1c[(size_t)t * 2048 + gl * 512 + (ni * 16 + c) * 8]);
            #pragma unroll
            for (int mi = 0; mi < 4; ++mi)
                a[mi] = *reinterpret_cast<const short8*>(
                    &Xc[(wm * 64 + mi * 16 + c) * 72 + k0 + gl * 8]);
            #pragma unroll
            for (int mi = 0; mi < 4; ++mi)
                #pragma unroll
                for (int ni = 0; ni < 4; ++ni)
                    acc[mi][ni] = __builtin_amdgcn_mfma_f32_16x16x32_bf16(a[mi], bb[ni], acc[mi][ni], 0, 0, 0);
        }
    }

    // epilogue: bias + relu -> H (sorted order, guarded rows)
    float bias1[4];
    #pragma unroll
    for (int ni = 0; ni < 4; ++ni) bias1[ni] = b1[s * CLIP + col0 + ni * 16 + c];
    #pragma unroll
    for (int mi = 0; mi < 4; ++mi)
        #pragma unroll
        for (int i = 0; i < 4; ++i) {
            int rl = wm * 64 + mi * 16 + gl * 4 + i;
            if (rl < nrows) {
                u16* hp = H + (size_t)(rowbase + rl) * CLIP + col0 + c;
                #pragma unroll
                for (int ni = 0; ni < 4; ++ni) {
                    float h = fmaxf(acc[mi][ni][i] + bias1[ni], 0.f);
                    hp[ni * 16] = f2bf(h);
                }
            }
        }
}

// ---- K2: Y = H @ W2 + b2, chunk=64 rows x panel=256 cols, pair-combined norm ----
__global__ __launch_bounds__(256) void gemm2_k(
    const float* __restrict__ b2, const u16* __restrict__ w2p,
    const int* __restrict__ meta, const u16* __restrict__ H,
    float* __restrict__ sqws, int* __restrict__ flags,
    float* __restrict__ out) {

    __shared__ u16 Hc[64 * 72];        // 9.2 KB
    __shared__ float partial[64 * 4];
    __shared__ float scalev[64];
    __shared__ int info[4];
    __shared__ int rowidx[64];
    __shared__ int cobuf[14], sobuf[14], totbuf[NSUB];

    int tid = threadIdx.x;

    int nwg = gridDim.x;
    int q = nwg >> 3, r = nwg & 7;
    int xcd = blockIdx.x & 7, idx = blockIdx.x >> 3;
    int bid = (xcd < r) ? xcd * (q + 1) + idx : r * (q + 1) + (xcd - r) * q + idx;
    int chunk = bid >> 1, panel = bid & 1;     // pair-sibs adjacent

    if (tid < 14) { cobuf[tid] = meta[M_C64 + tid]; sobuf[tid] = meta[M_SOFF + tid]; }
    if (tid < NSUB) totbuf[tid] = meta[M_TOT + tid];
    __syncthreads();
    if (tid == 0) {
        int total = cobuf[NSUB];
        if (chunk < total) {
            int s = 0;
            while (s < NSUB && !(chunk >= cobuf[s] && chunk < cobuf[s + 1])) s++;
            int ch = chunk - cobuf[s];
            info[0] = s;
            info[1] = sobuf[s] + ch * 64;
            info[2] = min(64, totbuf[s] - ch * 64);
        } else info[0] = -1;
    }
    __syncthreads();
    if (info[0] < 0) return;
    int s = info[0], rowbase = info[1], nrows = info[2];
    if (tid < 64) rowidx[tid] = meta[M_IDX + rowbase + min(tid, nrows - 1)];

    int wave = tid >> 6, lane = tid & 63;
    int c = lane & 15, gl = lane >> 4;
    int col0 = panel * 256 + wave * 64;
    const u16* w2c = w2p + (size_t)s * CLIP * CLIP + (size_t)(col0 >> 6) * 16 * 2048;

    f32x4 acc2[4][4];
    #pragma unroll
    for (int mi = 0; mi < 4; ++mi)
        #pragma unroll
        for (int ni = 0; ni < 4; ++ni)
            acc2[mi][ni] = (f32x4){0.f, 0.f, 0.f, 0.f};

    int srow = tid >> 2, sl4 = tid & 3;        // 64 rows, 4 thr/row, 2 short8 each

    for (int kc = 0; kc < 8; ++kc) {
        __syncthreads();
        {   // stage 64x64 H bf16 chunk
            int hrow = rowbase + min(srow, nrows - 1);
            const short8* hp = reinterpret_cast<const short8*>(
                H + (size_t)hrow * CLIP + kc * 64);
            *reinterpret_cast<short8*>(&Hc[srow * 72 + sl4 * 8])       = hp[sl4];
            *reinterpret_cast<short8*>(&Hc[srow * 72 + (sl4 + 4) * 8]) = hp[sl4 + 4];
        }
        __syncthreads();
        #pragma unroll
        for (int k0 = 0; k0 < 64; k0 += 32) {
            int t = kc * 2 + (k0 >> 5);
            short8 a[4], bb[4];
            #pragma unroll
            for (int ni = 0; ni < 4; ++ni)
                bb[ni] = *reinterpret_cast<const short8*>(
                    &w2c[(size_t)t * 2048 + gl * 512 + (ni * 16 + c) * 8]);
            #pragma unroll
            for (int mi = 0; mi < 4; ++mi)
                a[mi] = *reinterpret_cast<const short8*>(
                    &Hc[(mi * 16 + c) * 72 + k0 + gl * 8]);
            #pragma unroll
            for (int mi = 0; mi < 4; ++mi)
                #pragma unroll
                for (int ni = 0; ni < 4; ++ni)
                    acc2[mi][ni] = __builtin_amdgcn_mfma_f32_16x16x32_bf16(a[mi], bb[ni], acc2[mi][ni], 0, 0, 0);
        }
    }

    // bias + this panel's partial row sums of y^2
    float sq[4][4];
    {
        float bias2[4];
        #pragma unroll
        for (int ni = 0; ni < 4; ++ni) bias2[ni] = b2[s * CLIP + col0 + ni * 16 + c];
        #pragma unroll
        for (int mi = 0; mi < 4; ++mi)
            #pragma unroll
            for (int i = 0; i < 4; ++i) sq[mi][i] = 0.f;
        #pragma unroll
        for (int mi = 0; mi < 4; ++mi)
            #pragma unroll
            for (int ni = 0; ni < 4; ++ni)
                #pragma unroll
                for (int i = 0; i < 4; ++i) {
                    float v = acc2[mi][ni][i] + bias2[ni];
                    acc2[mi][ni][i] = v;
                    sq[mi][i] += v * v;
                }
    }
    #pragma unroll
    for (int m = 1; m < 16; m <<= 1)
        #pragma unroll
        for (int mi = 0; mi < 4; ++mi)
            #pragma unroll
            for (int i = 0; i < 4; ++i)
                sq[mi][i] += __shfl_xor(sq[mi][i], m);

    if (c == 0) {
        #pragma unroll
        for (int mi = 0; mi < 4; ++mi)
            #pragma unroll
            for (int i = 0; i < 4; ++i)
                partial[(mi * 16 + gl * 4 + i) * 4 + wave] = sq[mi][i];
    }
    __syncthreads();
    if (tid < 64) {
        float t = partial[tid * 4] + partial[tid * 4 + 1] +
                  partial[tid * 4 + 2] + partial[tid * 4 + 3];
        sqws[(size_t)chunk * 128 + panel * 64 + tid] = t;
    }
    __syncthreads();                   // drains the sqws stores
    if (tid == 0) {
        __threadfence();               // release
        atomicAdd(&flags[chunk], 1);
        while (__hip_atomic_load(&flags[chunk], __ATOMIC_ACQUIRE,
                                 __HIP_MEMORY_SCOPE_AGENT) < 2)
            __builtin_amdgcn_s_sleep(1);
    }
    __syncthreads();
    if (tid < 64) {
        // deterministic fixed-order sum of both panels' partials (L2-coherent loads)
        float p0 = __hip_atomic_load(&sqws[(size_t)chunk * 128 + tid],
                                     __ATOMIC_RELAXED, __HIP_MEMORY_SCOPE_AGENT);
        float p1 = __hip_atomic_load(&sqws[(size_t)chunk * 128 + 64 + tid],
                                     __ATOMIC_RELAXED, __HIP_MEMORY_SCOPE_AGENT);
        scalev[tid] = 1.f / fmaxf(sqrtf(p0 + p1), 1e-12f);
    }
    __syncthreads();

    #pragma unroll
    for (int mi = 0; mi < 4; ++mi)
        #pragma unroll
        for (int i = 0; i < 4; ++i) {
            int row = mi * 16 + gl * 4 + i;
            if (row < nrows) {
                float sc = scalev[row];
                float* op = out + (size_t)rowidx[row] * CLIP + col0 + c;
                #pragma unroll
                for (int ni = 0; ni < 4; ++ni)
                    op[ni * 16] = acc2[mi][ni][i] * sc;
            }
        }
}

extern "C" void kernel_launch(void* const* d_in, const int* in_sizes, int n_in,
                              void* d_out, int out_size, void* d_ws, size_t ws_size,
                              hipStream_t stream) {
    const float* eeg = (const float*)d_in[0];
    const int* sid   = (const int*)d_in[1];
    const float* W1  = (const float*)d_in[2];
    const float* b1  = (const float*)d_in[3];
    const float* W2  = (const float*)d_in[4];
    const float* b2  = (const float*)d_in[5];
    float* out = (float*)d_out;

    u16* w1p = (u16*)d_ws;                                   // 3.4 MB (packed)
    u16* w2p = w1p + (size_t)NSUB * CLIP * EEG;              // 6.8 MB (packed)
    u16* Hbuf = w2p + (size_t)NSUB * CLIP * CLIP;            // 16.8 MB (sorted order)
    int* meta = (int*)(Hbuf + (size_t)BATCH * CLIP);         // ~68 KB
    int* flags = meta + M_END;                               // 512 ints
    float* sqws = (float*)(flags + 512);                     // 270*128 floats

    convert_pack<<<1248, 256, 0, stream>>>(W1, W2, w1p, w2p, sid, meta);
    scanscatter_k<<<64, 256, 0, stream>>>(sid, meta, flags);
    gemm1_k<<<(BATCH / 128 + NSUB) * 4, 256, 0, stream>>>(eeg, b1, w1p, meta, Hbuf);
    gemm2_k<<<(BATCH / 64 + NSUB) * 2, 256, 0, stream>>>(b2, w2p, meta, Hbuf, sqws, flags, out);
}

// Round 10
// 83.471 us; speedup vs baseline: 1.0410x; 1.0410x over previous
//
#include <hip/hip_runtime.h>
#include <hip/hip_bf16.h>

// SubjectSpecificProjection: per-subject 2-layer MLP (256->512->512) + L2 normalize.
// R10: revert GEMMs to R7 shapes (best measured) + ONE variable: nontemporal
//      loads for all single-use streams (weights, H, X) and nt-stores for out.
//      Theory: per-CU ~27 GB/s weight-stream wall = L1 allocation serialization
//      (falsified: latency-depth, wave-count, block-count, block-size levers).
//      Pre-kernels stay fused (R8): convert_pack+hist, scanscatter. 4 launches.

#define BATCH 16384
#define EEG 256
#define CLIP 512
#define NSUB 13

// meta layout (ints):
#define M_BCNT 0        // [64][13]
#define M_SOFF 832      // [14] sample offsets per subject
#define M_TOT  846      // [13]
#define M_C128 859      // [14] 128-row chunk offsets
#define M_C64  873      // [14] 64-row chunk offsets
#define M_IDX  896      // [16384]

typedef unsigned short u16;
typedef __attribute__((ext_vector_type(8))) short short8;
typedef __attribute__((ext_vector_type(4))) float f32x4;

__device__ __forceinline__ u16 f2bf(float f) {
    union { float f; unsigned int u; } v; v.f = f;
    unsigned int u = v.u;
    unsigned int r = (u + 0x7FFFu + ((u >> 16) & 1u)) >> 16;   // RNE
    return (u16)r;
}

// ---- weight convert + pack (R7 layout) + fused histogram ----
// chunk(s,g,t) = 2048 u16 [slot(4)][colin(64)][e(8)]; element =
//   W[s][k = t*32 + slot*8 + e][n = g*64 + colin].
__global__ __launch_bounds__(256) void convert_pack(
    const float* __restrict__ W1, const float* __restrict__ W2,
    u16* __restrict__ w1p, u16* __restrict__ w2p,
    const int* __restrict__ sid, int* __restrict__ meta) {
    __shared__ u16 T[64][72];
    __shared__ int hh[NSUB];
    int b = blockIdx.x;
    const float* src; u16* dstbase; int ksteps;
    int s, kt, g;
    if (b < 416) {                     // W1: 13 x (4 kt)x(8 g)
        s = b >> 5; int t = b & 31;
        kt = t >> 3; g = t & 7;
        ksteps = 8;
        src = W1 + (size_t)s * EEG * CLIP;
        dstbase = w1p + (size_t)s * CLIP * EEG;
    } else {                           // W2: 13 x (8 kt)x(8 g)
        b -= 416; s = b >> 6; int t = b & 63;
        kt = t >> 3; g = t & 7;
        ksteps = 16;
        src = W2 + (size_t)s * CLIP * CLIP;
        dstbase = w2p + (size_t)s * CLIP * CLIP;
    }
    int k0 = kt << 6, n0 = g << 6;
    int tid = threadIdx.x;
    int rk = tid >> 2;
    int cg = (tid & 3) << 4;
    const f32x4* p4 = reinterpret_cast<const f32x4*>(src + (size_t)(k0 + rk) * CLIP + n0 + cg);
    #pragma unroll
    for (int jj = 0; jj < 4; ++jj) {
        f32x4 v = __builtin_nontemporal_load(p4 + jj);
        T[cg + jj * 4 + 0][rk] = f2bf(v[0]);
        T[cg + jj * 4 + 1][rk] = f2bf(v[1]);
        T[cg + jj * 4 + 2][rk] = f2bf(v[2]);
        T[cg + jj * 4 + 3][rk] = f2bf(v[3]);
    }
    __syncthreads();
    int colin = tid & 63, sl = (tid >> 6) & 3;
    #pragma unroll
    for (int half = 0; half < 2; ++half) {
        int t = kt * 2 + half;
        u16* dst = dstbase + ((size_t)(g * ksteps + t)) * 2048 + sl * 512 + colin * 8;
        *reinterpret_cast<short8*>(dst) =
            *reinterpret_cast<const short8*>(&T[colin][half * 32 + sl * 8]);
    }
    if (blockIdx.x < 64) {             // fused histogram
        if (tid < NSUB) hh[tid] = 0;
        __syncthreads();
        atomicAdd(&hh[sid[blockIdx.x * 256 + tid]], 1);
        __syncthreads();
        if (tid < NSUB) meta[M_BCNT + blockIdx.x * NSUB + tid] = hh[tid];
    }
}

// ---- scan + scatter in one kernel ----
__global__ __launch_bounds__(256) void scanscatter_k(
    const int* __restrict__ sid, int* __restrict__ meta) {
    __shared__ int cnt[64][NSUB];
    __shared__ int so[NSUB + 1], myoff[NSUB], tot[NSUB];
    __shared__ int h[NSUB];
    int tid = threadIdx.x;
    for (int i = tid; i < 64 * NSUB; i += 256)
        cnt[i / NSUB][i % NSUB] = meta[M_BCNT + i];
    if (tid < NSUB) h[tid] = 0;
    __syncthreads();
    if (tid < NSUB) {
        int run = 0, mine = 0;
        for (int b = 0; b < 64; ++b) {
            if (b == (int)blockIdx.x) mine = run;
            run += cnt[b][tid];
        }
        tot[tid] = run; myoff[tid] = mine;
    }
    __syncthreads();
    if (tid == 0) {
        int off = 0;
        for (int s = 0; s < NSUB; ++s) { so[s] = off; off += tot[s]; }
        so[NSUB] = off;
    }
    __syncthreads();
    if (blockIdx.x == 0) {
        if (tid < NSUB + 1) meta[M_SOFF + tid] = so[tid];
        if (tid < NSUB) meta[M_TOT + tid] = tot[tid];
        if (tid == 0) {
            int c128 = 0, c64 = 0;
            for (int s = 0; s < NSUB; ++s) {
                meta[M_C128 + s] = c128; meta[M_C64 + s] = c64;
                c128 += (tot[s] + 127) >> 7;
                c64  += (tot[s] + 63) >> 6;
            }
            meta[M_C128 + NSUB] = c128;
            meta[M_C64 + NSUB] = c64;
        }
    }
    int i = blockIdx.x * 256 + tid;
    int s = sid[i];
    int r = atomicAdd(&h[s], 1);
    meta[M_IDX + so[s] + myoff[s] + r] = i;
}

// ---- K1: H = relu(X @ W1 + b1). M=128 x panel=256, 512 thr (R7 shape) ----
__global__ __launch_bounds__(512) void gemm1_k(
    const float* __restrict__ X, const float* __restrict__ b1,
    const u16* __restrict__ w1p, const int* __restrict__ meta,
    u16* __restrict__ H) {

    __shared__ u16 Xc[128 * 72];       // 18.4 KB
    __shared__ int info[4];
    __shared__ int rowidx[128];
    __shared__ int cobuf[14], sobuf[14], totbuf[NSUB];

    int tid = threadIdx.x;

    int nwg = gridDim.x;
    int q = nwg >> 3, r = nwg & 7;
    int xcd = blockIdx.x & 7, idx = blockIdx.x >> 3;
    int bid = (xcd < r) ? xcd * (q + 1) + idx : r * (q + 1) + (xcd - r) * q + idx;
    int chunk = bid >> 1, panel = bid & 1;

    if (tid < 14) { cobuf[tid] = meta[M_C128 + tid]; sobuf[tid] = meta[M_SOFF + tid]; }
    if (tid < NSUB) totbuf[tid] = meta[M_TOT + tid];
    __syncthreads();
    if (tid == 0) {
        int total = cobuf[NSUB];
        if (chunk < total) {
            int s = 0;
            while (s < NSUB && !(chunk >= cobuf[s] && chunk < cobuf[s + 1])) s++;
            int ch = chunk - cobuf[s];
            info[0] = s;
            info[1] = sobuf[s] + ch * 128;
            info[2] = min(128, totbuf[s] - ch * 128);
        } else info[0] = -1;
    }
    __syncthreads();
    if (info[0] < 0) return;
    int s = info[0], rowbase = info[1], nrows = info[2];
    if (tid < 128) rowidx[tid] = meta[M_IDX + rowbase + min(tid, nrows - 1)];

    int wave = tid >> 6, lane = tid & 63;
    int c = lane & 15, gl = lane >> 4;
    int wm = wave >> 2, wn = wave & 3;     // 2M x 4N
    int col0 = panel * 256 + wn * 64;
    const u16* w1c = w1p + (size_t)s * CLIP * EEG + (size_t)(col0 >> 6) * 8 * 2048;

    f32x4 acc[4][4];
    #pragma unroll
    for (int mi = 0; mi < 4; ++mi)
        #pragma unroll
        for (int ni = 0; ni < 4; ++ni)
            acc[mi][ni] = (f32x4){0.f, 0.f, 0.f, 0.f};

    int srow = tid >> 2, sl4 = tid & 3;    // 128 rows, 4 thr/row

    for (int kc = 0; kc < 4; ++kc) {
        __syncthreads();
        {   // stage 128x64 X chunk, fp32 -> bf16 (nt loads: single-use stream)
            const f32x4* xp = reinterpret_cast<const f32x4*>(
                X + (size_t)rowidx[srow] * EEG) + kc * 16 + sl4 * 4;
            u16* xd = &Xc[srow * 72 + sl4 * 16];
            #pragma unroll
            for (int j = 0; j < 4; ++j) {
                f32x4 v = __builtin_nontemporal_load(xp + j);
                union { u16 u[4]; uint2 qq; } pk;
                pk.u[0] = f2bf(v[0]); pk.u[1] = f2bf(v[1]);
                pk.u[2] = f2bf(v[2]); pk.u[3] = f2bf(v[3]);
                *reinterpret_cast<uint2*>(&xd[j * 4]) = pk.qq;
            }
        }
        __syncthreads();
        #pragma unroll
        for (int k0 = 0; k0 < 64; k0 += 32) {
            int t = kc * 2 + (k0 >> 5);
            short8 a[4], bb[4];
            #pragma unroll
            for (int ni = 0; ni < 4; ++ni)
                bb[ni] = __builtin_nontemporal_load(reinterpret_cast<const short8*>(
                    &w1c[(size_t)t * 2048 + gl * 512 + (ni * 16 + c) * 8]));
            #pragma unroll
            for (int mi = 0; mi < 4; ++mi)
                a[mi] = *reinterpret_cast<const short8*>(
                    &Xc[(wm * 64 + mi * 16 + c) * 72 + k0 + gl * 8]);
            #pragma unroll
            for (int mi = 0; mi < 4; ++mi)
                #pragma unroll
                for (int ni = 0; ni < 4; ++ni)
                    acc[mi][ni] = __builtin_amdgcn_mfma_f32_16x16x32_bf16(a[mi], bb[ni], acc[mi][ni], 0, 0, 0);
        }
    }

    // epilogue: bias + relu -> H (sorted order, guarded rows)
    float bias1[4];
    #pragma unroll
    for (int ni = 0; ni < 4; ++ni) bias1[ni] = b1[s * CLIP + col0 + ni * 16 + c];
    #pragma unroll
    for (int mi = 0; mi < 4; ++mi)
        #pragma unroll
        for (int i = 0; i < 4; ++i) {
            int rl = wm * 64 + mi * 16 + gl * 4 + i;
            if (rl < nrows) {
                u16* hp = H + (size_t)(rowbase + rl) * CLIP + col0 + c;
                #pragma unroll
                for (int ni = 0; ni < 4; ++ni) {
                    float h = fmaxf(acc[mi][ni][i] + bias1[ni], 0.f);
                    hp[ni * 16] = f2bf(h);
                }
            }
        }
}

// ---- K2: Y = H @ W2 + b2, L2-normalize, scatter. M=64 x full N, 512 thr (R7) ----
__global__ __launch_bounds__(512) void gemm2_k(
    const float* __restrict__ b2, const u16* __restrict__ w2p,
    const int* __restrict__ meta, const u16* __restrict__ H,
    float* __restrict__ out) {

    __shared__ u16 Hs[64 * 520];       // 66.6 KB
    __shared__ float partial[64 * 8];
    __shared__ float scalev[64];
    __shared__ int info[4];
    __shared__ int rowidx[64];
    __shared__ int cobuf[14], sobuf[14], totbuf[NSUB];

    int tid = threadIdx.x;

    int nwg = gridDim.x;
    int q = nwg >> 3, r = nwg & 7;
    int xcd = blockIdx.x & 7, idx = blockIdx.x >> 3;
    int bid = (xcd < r) ? xcd * (q + 1) + idx : r * (q + 1) + (xcd - r) * q + idx;

    if (tid < 14) { cobuf[tid] = meta[M_C64 + tid]; sobuf[tid] = meta[M_SOFF + tid]; }
    if (tid < NSUB) totbuf[tid] = meta[M_TOT + tid];
    __syncthreads();
    if (tid == 0) {
        int total = cobuf[NSUB];
        if (bid < total) {
            int s = 0;
            while (s < NSUB && !(bid >= cobuf[s] && bid < cobuf[s + 1])) s++;
            int chunk = bid - cobuf[s];
            info[0] = s;
            info[1] = sobuf[s] + chunk * 64;
            info[2] = min(64, totbuf[s] - chunk * 64);
        } else info[0] = -1;
    }
    __syncthreads();
    if (info[0] < 0) return;
    int s = info[0], rowbase = info[1], nrows = info[2];

    if (tid < 64) rowidx[tid] = meta[M_IDX + rowbase + min(tid, nrows - 1)];

    // stage H tile (sorted rows, nt loads: single-use stream)
    {
        int row = tid >> 3, l8 = tid & 7;
        int hrow = rowbase + min(row, nrows - 1);
        const short8* hp = reinterpret_cast<const short8*>(H + (size_t)hrow * CLIP);
        #pragma unroll
        for (int it = 0; it < 8; ++it) {
            int cg = l8 + it * 8;
            *reinterpret_cast<short8*>(&Hs[row * 520 + cg * 8]) =
                __builtin_nontemporal_load(hp + cg);
        }
    }
    __syncthreads();

    int wave = tid >> 6;
    int lane = tid & 63;
    int c = lane & 15;
    int gl = lane >> 4;
    int wn0 = wave * 64;
    const u16* w2c = w2p + (size_t)s * CLIP * CLIP + (size_t)(wn0 >> 6) * 16 * 2048;

    f32x4 acc2[4][4];
    #pragma unroll
    for (int mi = 0; mi < 4; ++mi)
        #pragma unroll
        for (int ni = 0; ni < 4; ++ni)
            acc2[mi][ni] = (f32x4){0.f, 0.f, 0.f, 0.f};

    #pragma unroll 4
    for (int k0 = 0; k0 < CLIP; k0 += 32) {
        int t = k0 >> 5;
        short8 a[4], bb[4];
        #pragma unroll
        for (int ni = 0; ni < 4; ++ni)
            bb[ni] = __builtin_nontemporal_load(reinterpret_cast<const short8*>(
                &w2c[(size_t)t * 2048 + gl * 512 + (ni * 16 + c) * 8]));
        #pragma unroll
        for (int mi = 0; mi < 4; ++mi)
            a[mi] = *reinterpret_cast<const short8*>(&Hs[(mi * 16 + c) * 520 + k0 + gl * 8]);
        #pragma unroll
        for (int mi = 0; mi < 4; ++mi)
            #pragma unroll
            for (int ni = 0; ni < 4; ++ni)
                acc2[mi][ni] = __builtin_amdgcn_mfma_f32_16x16x32_bf16(a[mi], bb[ni], acc2[mi][ni], 0, 0, 0);
    }

    // bias + squared row-sums (this wave's 64 cols)
    float sq[4][4];
    {
        float bias2[4];
        #pragma unroll
        for (int ni = 0; ni < 4; ++ni) bias2[ni] = b2[s * CLIP + wn0 + ni * 16 + c];
        #pragma unroll
        for (int mi = 0; mi < 4; ++mi)
            #pragma unroll
            for (int i = 0; i < 4; ++i) sq[mi][i] = 0.f;
        #pragma unroll
        for (int mi = 0; mi < 4; ++mi)
            #pragma unroll
            for (int ni = 0; ni < 4; ++ni)
                #pragma unroll
                for (int i = 0; i < 4; ++i) {
                    float v = acc2[mi][ni][i] + bias2[ni];
                    acc2[mi][ni][i] = v;
                    sq[mi][i] += v * v;
                }
    }
    #pragma unroll
    for (int m = 1; m < 16; m <<= 1)
        #pragma unroll
        for (int mi = 0; mi < 4; ++mi)
            #pragma unroll
            for (int i = 0; i < 4; ++i)
                sq[mi][i] += __shfl_xor(sq[mi][i], m);

    if (c == 0) {
        #pragma unroll
        for (int mi = 0; mi < 4; ++mi)
            #pragma unroll
            for (int i = 0; i < 4; ++i)
                partial[(mi * 16 + gl * 4 + i) * 8 + wave] = sq[mi][i];
    }
    __syncthreads();
    if (tid < 64) {
        float t = 0.f;
        #pragma unroll
        for (int w = 0; w < 8; ++w) t += partial[tid * 8 + w];
        scalev[tid] = 1.f / fmaxf(sqrtf(t), 1e-12f);
    }
    __syncthreads();

    #pragma unroll
    for (int mi = 0; mi < 4; ++mi)
        #pragma unroll
        for (int i = 0; i < 4; ++i) {
            int row = mi * 16 + gl * 4 + i;
            if (row < nrows) {
                float sc = scalev[row];
                float* op = out + (size_t)rowidx[row] * CLIP + wn0 + c;
                #pragma unroll
                for (int ni = 0; ni < 4; ++ni)
                    __builtin_nontemporal_store(acc2[mi][ni][i] * sc, op + ni * 16);
            }
        }
}

extern "C" void kernel_launch(void* const* d_in, const int* in_sizes, int n_in,
                              void* d_out, int out_size, void* d_ws, size_t ws_size,
                              hipStream_t stream) {
    const float* eeg = (const float*)d_in[0];
    const int* sid   = (const int*)d_in[1];
    const float* W1  = (const float*)d_in[2];
    const float* b1  = (const float*)d_in[3];
    const float* W2  = (const float*)d_in[4];
    const float* b2  = (const float*)d_in[5];
    float* out = (float*)d_out;

    u16* w1p = (u16*)d_ws;                                   // 3.4 MB (packed)
    u16* w2p = w1p + (size_t)NSUB * CLIP * EEG;              // 6.8 MB (packed)
    u16* Hbuf = w2p + (size_t)NSUB * CLIP * CLIP;            // 16.8 MB (sorted order)
    int* meta = (int*)(Hbuf + (size_t)BATCH * CLIP);         // ~68 KB

    convert_pack<<<1248, 256, 0, stream>>>(W1, W2, w1p, w2p, sid, meta);
    scanscatter_k<<<64, 256, 0, stream>>>(sid, meta);
    gemm1_k<<<(BATCH / 128 + NSUB) * 2, 512, 0, stream>>>(eeg, b1, w1p, meta, Hbuf);
    gemm2_k<<<BATCH / 64 + NSUB, 512, 0, stream>>>(b2, w2p, meta, Hbuf, out);
}

// Round 11
// 66.000 us; speedup vs baseline: 1.3166x; 1.2647x over previous
//
#include <hip/hip_runtime.h>
#include <hip/hip_bf16.h>

// SubjectSpecificProjection: per-subject 2-layer MLP (256->512->512) + L2 normalize.
// R11: revert nt loads (R10: -18us, weights/H are L2-reused). Base = R8.
//      gemm2 back to M=64/fullN/512thr (barrier-free k-loop) + ONE new mechanism:
//      manual depth-1 register double-buffer of the weight stream (unroll-2,
//      bbA/bbB; launch_bounds(512,2) grants ~176-reg budget). nt-store out only.

#define BATCH 16384
#define EEG 256
#define CLIP 512
#define NSUB 13

// meta layout (ints):
#define M_BCNT 0        // [64][13]
#define M_SOFF 832      // [14] sample offsets per subject
#define M_TOT  846      // [13]
#define M_C256 859      // [14] 256-row chunk offsets (gemm1)
#define M_C64  873      // [14] 64-row chunk offsets (gemm2)
#define M_IDX  896      // [16384]

typedef unsigned short u16;
typedef __attribute__((ext_vector_type(8))) short short8;
typedef __attribute__((ext_vector_type(4))) float f32x4;

__device__ __forceinline__ u16 f2bf(float f) {
    union { float f; unsigned int u; } v; v.f = f;
    unsigned int u = v.u;
    unsigned int r = (u + 0x7FFFu + ((u >> 16) & 1u)) >> 16;   // RNE
    return (u16)r;
}

// ---- weight convert + pack (R7 layout) + fused histogram ----
// chunk(s,g,t) = 2048 u16 [slot(4)][colin(64)][e(8)]; element =
//   W[s][k = t*32 + slot*8 + e][n = g*64 + colin].
__global__ __launch_bounds__(256) void convert_pack(
    const float* __restrict__ W1, const float* __restrict__ W2,
    u16* __restrict__ w1p, u16* __restrict__ w2p,
    const int* __restrict__ sid, int* __restrict__ meta) {
    __shared__ u16 T[64][72];
    __shared__ int hh[NSUB];
    int b = blockIdx.x;
    const float* src; u16* dstbase; int ksteps;
    int s, kt, g;
    if (b < 416) {                     // W1: 13 x (4 kt)x(8 g)
        s = b >> 5; int t = b & 31;
        kt = t >> 3; g = t & 7;
        ksteps = 8;
        src = W1 + (size_t)s * EEG * CLIP;
        dstbase = w1p + (size_t)s * CLIP * EEG;
    } else {                           // W2: 13 x (8 kt)x(8 g)
        b -= 416; s = b >> 6; int t = b & 63;
        kt = t >> 3; g = t & 7;
        ksteps = 16;
        src = W2 + (size_t)s * CLIP * CLIP;
        dstbase = w2p + (size_t)s * CLIP * CLIP;
    }
    int k0 = kt << 6, n0 = g << 6;
    int tid = threadIdx.x;
    int rk = tid >> 2;
    int cg = (tid & 3) << 4;
    const float4* p4 = reinterpret_cast<const float4*>(src + (size_t)(k0 + rk) * CLIP + n0 + cg);
    #pragma unroll
    for (int jj = 0; jj < 4; ++jj) {
        float4 v = p4[jj];
        T[cg + jj * 4 + 0][rk] = f2bf(v.x);
        T[cg + jj * 4 + 1][rk] = f2bf(v.y);
        T[cg + jj * 4 + 2][rk] = f2bf(v.z);
        T[cg + jj * 4 + 3][rk] = f2bf(v.w);
    }
    __syncthreads();
    int colin = tid & 63, sl = (tid >> 6) & 3;
    #pragma unroll
    for (int half = 0; half < 2; ++half) {
        int t = kt * 2 + half;
        u16* dst = dstbase + ((size_t)(g * ksteps + t)) * 2048 + sl * 512 + colin * 8;
        *reinterpret_cast<short8*>(dst) =
            *reinterpret_cast<const short8*>(&T[colin][half * 32 + sl * 8]);
    }
    if (blockIdx.x < 64) {             // fused histogram
        if (tid < NSUB) hh[tid] = 0;
        __syncthreads();
        atomicAdd(&hh[sid[blockIdx.x * 256 + tid]], 1);
        __syncthreads();
        if (tid < NSUB) meta[M_BCNT + blockIdx.x * NSUB + tid] = hh[tid];
    }
}

// ---- scan + scatter in one kernel ----
__global__ __launch_bounds__(256) void scanscatter_k(
    const int* __restrict__ sid, int* __restrict__ meta) {
    __shared__ int cnt[64][NSUB];
    __shared__ int so[NSUB + 1], myoff[NSUB], tot[NSUB];
    __shared__ int h[NSUB];
    int tid = threadIdx.x;
    for (int i = tid; i < 64 * NSUB; i += 256)
        cnt[i / NSUB][i % NSUB] = meta[M_BCNT + i];
    if (tid < NSUB) h[tid] = 0;
    __syncthreads();
    if (tid < NSUB) {
        int run = 0, mine = 0;
        for (int b = 0; b < 64; ++b) {
            if (b == (int)blockIdx.x) mine = run;
            run += cnt[b][tid];
        }
        tot[tid] = run; myoff[tid] = mine;
    }
    __syncthreads();
    if (tid == 0) {
        int off = 0;
        for (int s = 0; s < NSUB; ++s) { so[s] = off; off += tot[s]; }
        so[NSUB] = off;
    }
    __syncthreads();
    if (blockIdx.x == 0) {
        if (tid < NSUB + 1) meta[M_SOFF + tid] = so[tid];
        if (tid < NSUB) meta[M_TOT + tid] = tot[tid];
        if (tid == 0) {
            int c256 = 0, c64 = 0;
            for (int s = 0; s < NSUB; ++s) {
                meta[M_C256 + s] = c256; meta[M_C64 + s] = c64;
                c256 += (tot[s] + 255) >> 8;
                c64  += (tot[s] + 63) >> 6;
            }
            meta[M_C256 + NSUB] = c256;
            meta[M_C64 + NSUB] = c64;
        }
    }
    int i = blockIdx.x * 256 + tid;
    int s = sid[i];
    int r = atomicAdd(&h[s], 1);
    meta[M_IDX + so[s] + myoff[s] + r] = i;
}

// ---- K1: H = relu(X @ W1 + b1). M=256 x panel=256, 1024 thr, waves 4Mx4N ----
__global__ __launch_bounds__(1024) void gemm1_k(
    const float* __restrict__ X, const float* __restrict__ b1,
    const u16* __restrict__ w1p, const int* __restrict__ meta,
    u16* __restrict__ H) {

    __shared__ u16 Xc[256 * 72];       // 36.9 KB
    __shared__ int info[4];
    __shared__ int rowidx[256];
    __shared__ int cobuf[14], sobuf[14], totbuf[NSUB];

    int tid = threadIdx.x;

    int nwg = gridDim.x;
    int q = nwg >> 3, r = nwg & 7;
    int xcd = blockIdx.x & 7, idx = blockIdx.x >> 3;
    int bid = (xcd < r) ? xcd * (q + 1) + idx : r * (q + 1) + (xcd - r) * q + idx;
    int chunk = bid >> 1, panel = bid & 1;

    if (tid < 14) { cobuf[tid] = meta[M_C256 + tid]; sobuf[tid] = meta[M_SOFF + tid]; }
    if (tid < NSUB) totbuf[tid] = meta[M_TOT + tid];
    __syncthreads();
    if (tid == 0) {
        int total = cobuf[NSUB];
        if (chunk < total) {
            int s = 0;
            while (s < NSUB && !(chunk >= cobuf[s] && chunk < cobuf[s + 1])) s++;
            int ch = chunk - cobuf[s];
            info[0] = s;
            info[1] = sobuf[s] + ch * 256;
            info[2] = min(256, totbuf[s] - ch * 256);
        } else info[0] = -1;
    }
    __syncthreads();
    if (info[0] < 0) return;
    int s = info[0], rowbase = info[1], nrows = info[2];
    if (tid < 256) rowidx[tid] = meta[M_IDX + rowbase + min(tid, nrows - 1)];

    int wave = tid >> 6, lane = tid & 63;
    int c = lane & 15, gl = lane >> 4;
    int wm = wave >> 2, wn = wave & 3;     // 4M x 4N
    int col0 = panel * 256 + wn * 64;
    const u16* w1c = w1p + (size_t)s * CLIP * EEG + (size_t)(col0 >> 6) * 8 * 2048;

    f32x4 acc[4][4];
    #pragma unroll
    for (int mi = 0; mi < 4; ++mi)
        #pragma unroll
        for (int ni = 0; ni < 4; ++ni)
            acc[mi][ni] = (f32x4){0.f, 0.f, 0.f, 0.f};

    int srow = tid >> 2, sl4 = tid & 3;    // 256 rows, 4 threads/row

    for (int kc = 0; kc < 4; ++kc) {
        __syncthreads();
        {   // stage 256x64 X chunk, fp32 -> bf16
            const float4* xp = reinterpret_cast<const float4*>(
                X + (size_t)rowidx[srow] * EEG) + kc * 16 + sl4 * 4;
            u16* xd = &Xc[srow * 72 + sl4 * 16];
            #pragma unroll
            for (int j = 0; j < 4; ++j) {
                float4 v = xp[j];
                union { u16 u[4]; uint2 qq; } pk;
                pk.u[0] = f2bf(v.x); pk.u[1] = f2bf(v.y);
                pk.u[2] = f2bf(v.z); pk.u[3] = f2bf(v.w);
                *reinterpret_cast<uint2*>(&xd[j * 4]) = pk.qq;
            }
        }
        __syncthreads();
        #pragma unroll
        for (int k0 = 0; k0 < 64; k0 += 32) {
            int t = kc * 2 + (k0 >> 5);
            short8 a[4], bb[4];
            #pragma unroll
            for (int ni = 0; ni < 4; ++ni)
                bb[ni] = *reinterpret_cast<const short8*>(
                    &w1c[(size_t)t * 2048 + gl * 512 + (ni * 16 + c) * 8]);
            #pragma unroll
            for (int mi = 0; mi < 4; ++mi)
                a[mi] = *reinterpret_cast<const short8*>(
                    &Xc[(wm * 64 + mi * 16 + c) * 72 + k0 + gl * 8]);
            #pragma unroll
            for (int mi = 0; mi < 4; ++mi)
                #pragma unroll
                for (int ni = 0; ni < 4; ++ni)
                    acc[mi][ni] = __builtin_amdgcn_mfma_f32_16x16x32_bf16(a[mi], bb[ni], acc[mi][ni], 0, 0, 0);
        }
    }

    // epilogue: bias + relu -> H (sorted order, guarded rows)
    float bias1[4];
    #pragma unroll
    for (int ni = 0; ni < 4; ++ni) bias1[ni] = b1[s * CLIP + col0 + ni * 16 + c];
    #pragma unroll
    for (int mi = 0; mi < 4; ++mi)
        #pragma unroll
        for (int i = 0; i < 4; ++i) {
            int rl = wm * 64 + mi * 16 + gl * 4 + i;
            if (rl < nrows) {
                u16* hp = H + (size_t)(rowbase + rl) * CLIP + col0 + c;
                #pragma unroll
                for (int ni = 0; ni < 4; ++ni) {
                    float h = fmaxf(acc[mi][ni][i] + bias1[ni], 0.f);
                    hp[ni * 16] = f2bf(h);
                }
            }
        }
}

// ---- K2: Y = H @ W2 + b2, L2-normalize, scatter. M=64 x full N, 512 thr ----
//      Barrier-free k-loop + manual depth-1 register dbuf of the weight stream.
__global__ __launch_bounds__(512, 2) void gemm2_k(
    const float* __restrict__ b2, const u16* __restrict__ w2p,
    const int* __restrict__ meta, const u16* __restrict__ H,
    float* __restrict__ out) {

    __shared__ u16 Hs[64 * 520];       // 66.6 KB
    __shared__ float partial[64 * 8];
    __shared__ float scalev[64];
    __shared__ int info[4];
    __shared__ int rowidx[64];
    __shared__ int cobuf[14], sobuf[14], totbuf[NSUB];

    int tid = threadIdx.x;

    int nwg = gridDim.x;
    int q = nwg >> 3, r = nwg & 7;
    int xcd = blockIdx.x & 7, idx = blockIdx.x >> 3;
    int bid = (xcd < r) ? xcd * (q + 1) + idx : r * (q + 1) + (xcd - r) * q + idx;

    if (tid < 14) { cobuf[tid] = meta[M_C64 + tid]; sobuf[tid] = meta[M_SOFF + tid]; }
    if (tid < NSUB) totbuf[tid] = meta[M_TOT + tid];
    __syncthreads();
    if (tid == 0) {
        int total = cobuf[NSUB];
        if (bid < total) {
            int s = 0;
            while (s < NSUB && !(bid >= cobuf[s] && bid < cobuf[s + 1])) s++;
            int chunk = bid - cobuf[s];
            info[0] = s;
            info[1] = sobuf[s] + chunk * 64;
            info[2] = min(64, totbuf[s] - chunk * 64);
        } else info[0] = -1;
    }
    __syncthreads();
    if (info[0] < 0) return;
    int s = info[0], rowbase = info[1], nrows = info[2];

    if (tid < 64) rowidx[tid] = meta[M_IDX + rowbase + min(tid, nrows - 1)];

    // stage H tile (sorted rows -> coalesced bf16 reads)
    {
        int row = tid >> 3, l8 = tid & 7;
        int hrow = rowbase + min(row, nrows - 1);
        const short8* hp = reinterpret_cast<const short8*>(H + (size_t)hrow * CLIP);
        #pragma unroll
        for (int it = 0; it < 8; ++it) {
            int cg = l8 + it * 8;
            *reinterpret_cast<short8*>(&Hs[row * 520 + cg * 8]) = hp[cg];
        }
    }
    __syncthreads();

    int wave = tid >> 6;
    int lane = tid & 63;
    int c = lane & 15;
    int gl = lane >> 4;
    int wn0 = wave * 64;
    const u16* w2c = w2p + (size_t)s * CLIP * CLIP + (size_t)(wn0 >> 6) * 16 * 2048;

    f32x4 acc2[4][4];
    #pragma unroll
    for (int mi = 0; mi < 4; ++mi)
        #pragma unroll
        for (int ni = 0; ni < 4; ++ni)
            acc2[mi][ni] = (f32x4){0.f, 0.f, 0.f, 0.f};

    // barrier-free k-loop, 16 steps, manual weight double-buffer (unroll-2)
    short8 bbA[4], bbB[4];
    #pragma unroll
    for (int ni = 0; ni < 4; ++ni)
        bbA[ni] = *reinterpret_cast<const short8*>(
            &w2c[(size_t)0 * 2048 + gl * 512 + (ni * 16 + c) * 8]);
    #pragma unroll
    for (int tp = 0; tp < 8; ++tp) {
        int t0 = tp * 2;
        // prefetch t0+1 before consuming t0
        #pragma unroll
        for (int ni = 0; ni < 4; ++ni)
            bbB[ni] = *reinterpret_cast<const short8*>(
                &w2c[(size_t)(t0 + 1) * 2048 + gl * 512 + (ni * 16 + c) * 8]);
        {
            short8 a[4];
            #pragma unroll
            for (int mi = 0; mi < 4; ++mi)
                a[mi] = *reinterpret_cast<const short8*>(
                    &Hs[(mi * 16 + c) * 520 + t0 * 32 + gl * 8]);
            #pragma unroll
            for (int mi = 0; mi < 4; ++mi)
                #pragma unroll
                for (int ni = 0; ni < 4; ++ni)
                    acc2[mi][ni] = __builtin_amdgcn_mfma_f32_16x16x32_bf16(a[mi], bbA[ni], acc2[mi][ni], 0, 0, 0);
        }
        // prefetch t0+2 before consuming t0+1
        if (tp < 7) {
            #pragma unroll
            for (int ni = 0; ni < 4; ++ni)
                bbA[ni] = *reinterpret_cast<const short8*>(
                    &w2c[(size_t)(t0 + 2) * 2048 + gl * 512 + (ni * 16 + c) * 8]);
        }
        {
            short8 a[4];
            #pragma unroll
            for (int mi = 0; mi < 4; ++mi)
                a[mi] = *reinterpret_cast<const short8*>(
                    &Hs[(mi * 16 + c) * 520 + (t0 + 1) * 32 + gl * 8]);
            #pragma unroll
            for (int mi = 0; mi < 4; ++mi)
                #pragma unroll
                for (int ni = 0; ni < 4; ++ni)
                    acc2[mi][ni] = __builtin_amdgcn_mfma_f32_16x16x32_bf16(a[mi], bbB[ni], acc2[mi][ni], 0, 0, 0);
        }
    }

    // bias + squared row-sums (this wave's 64 cols)
    float sq[4][4];
    {
        float bias2[4];
        #pragma unroll
        for (int ni = 0; ni < 4; ++ni) bias2[ni] = b2[s * CLIP + wn0 + ni * 16 + c];
        #pragma unroll
        for (int mi = 0; mi < 4; ++mi)
            #pragma unroll
            for (int i = 0; i < 4; ++i) sq[mi][i] = 0.f;
        #pragma unroll
        for (int mi = 0; mi < 4; ++mi)
            #pragma unroll
            for (int ni = 0; ni < 4; ++ni)
                #pragma unroll
                for (int i = 0; i < 4; ++i) {
                    float v = acc2[mi][ni][i] + bias2[ni];
                    acc2[mi][ni][i] = v;
                    sq[mi][i] += v * v;
                }
    }
    #pragma unroll
    for (int m = 1; m < 16; m <<= 1)
        #pragma unroll
        for (int mi = 0; mi < 4; ++mi)
            #pragma unroll
            for (int i = 0; i < 4; ++i)
                sq[mi][i] += __shfl_xor(sq[mi][i], m);

    if (c == 0) {
        #pragma unroll
        for (int mi = 0; mi < 4; ++mi)
            #pragma unroll
            for (int i = 0; i < 4; ++i)
                partial[(mi * 16 + gl * 4 + i) * 8 + wave] = sq[mi][i];
    }
    __syncthreads();
    if (tid < 64) {
        float t = 0.f;
        #pragma unroll
        for (int w = 0; w < 8; ++w) t += partial[tid * 8 + w];
        scalev[tid] = 1.f / fmaxf(sqrtf(t), 1e-12f);
    }
    __syncthreads();

    #pragma unroll
    for (int mi = 0; mi < 4; ++mi)
        #pragma unroll
        for (int i = 0; i < 4; ++i) {
            int row = mi * 16 + gl * 4 + i;
            if (row < nrows) {
                float sc = scalev[row];
                float* op = out + (size_t)rowidx[row] * CLIP + wn0 + c;
                #pragma unroll
                for (int ni = 0; ni < 4; ++ni)
                    __builtin_nontemporal_store(acc2[mi][ni][i] * sc, op + ni * 16);
            }
        }
}

extern "C" void kernel_launch(void* const* d_in, const int* in_sizes, int n_in,
                              void* d_out, int out_size, void* d_ws, size_t ws_size,
                              hipStream_t stream) {
    const float* eeg = (const float*)d_in[0];
    const int* sid   = (const int*)d_in[1];
    const float* W1  = (const float*)d_in[2];
    const float* b1  = (const float*)d_in[3];
    const float* W2  = (const float*)d_in[4];
    const float* b2  = (const float*)d_in[5];
    float* out = (float*)d_out;

    u16* w1p = (u16*)d_ws;                                   // 3.4 MB (packed)
    u16* w2p = w1p + (size_t)NSUB * CLIP * EEG;              // 6.8 MB (packed)
    u16* Hbuf = w2p + (size_t)NSUB * CLIP * CLIP;            // 16.8 MB (sorted order)
    int* meta = (int*)(Hbuf + (size_t)BATCH * CLIP);         // ~68 KB

    convert_pack<<<1248, 256, 0, stream>>>(W1, W2, w1p, w2p, sid, meta);
    scanscatter_k<<<64, 256, 0, stream>>>(sid, meta);
    gemm1_k<<<(BATCH / 256 + NSUB) * 2, 1024, 0, stream>>>(eeg, b1, w1p, meta, Hbuf);
    gemm2_k<<<BATCH / 64 + NSUB, 512, 0, stream>>>(b2, w2p, meta, Hbuf, out);
}

// Round 12
// 49.940 us; speedup vs baseline: 1.7400x; 1.3216x over previous
//
#include <hip/hip_runtime.h>
#include <hip/hip_bf16.h>

// SubjectSpecificProjection: per-subject 2-layer MLP (256->512->512) + L2 normalize.
// R12: RE-FUSE with packed weights. Split-era accounting doesn't close (R8 sum
//      ~46 vs 65 measured) -> pay hidden costs: H round-trip (33.6MB HBM), dual
//      staging/epilogues, two makespans. Fused M=128: 896 KB/block, 141 blocks,
//      1 block/CU, one round, 3 launches. LDS union: Xc aliases Hs head (R2),
//      138 KB total. 16 waves = 2M x 8N, acc[4][4].

#define BATCH 16384
#define EEG 256
#define CLIP 512
#define NSUB 13

// meta layout (ints):
#define M_BCNT 0        // [64][13]
#define M_SOFF 832      // [14] sample offsets per subject
#define M_TOT  846      // [13]
#define M_C128 859      // [14] 128-row chunk offsets
#define M_IDX  896      // [16384]

typedef unsigned short u16;
typedef __attribute__((ext_vector_type(8))) short short8;
typedef __attribute__((ext_vector_type(4))) float f32x4;

__device__ __forceinline__ u16 f2bf(float f) {
    union { float f; unsigned int u; } v; v.f = f;
    unsigned int u = v.u;
    unsigned int r = (u + 0x7FFFu + ((u >> 16) & 1u)) >> 16;   // RNE
    return (u16)r;
}

// ---- weight convert + pack (R7 layout) + fused histogram ----
// chunk(s,g,t) = 2048 u16 [slot(4)][colin(64)][e(8)]; element =
//   W[s][k = t*32 + slot*8 + e][n = g*64 + colin].
__global__ __launch_bounds__(256) void convert_pack(
    const float* __restrict__ W1, const float* __restrict__ W2,
    u16* __restrict__ w1p, u16* __restrict__ w2p,
    const int* __restrict__ sid, int* __restrict__ meta) {
    __shared__ u16 T[64][72];
    __shared__ int hh[NSUB];
    int b = blockIdx.x;
    const float* src; u16* dstbase; int ksteps;
    int s, kt, g;
    if (b < 416) {                     // W1: 13 x (4 kt)x(8 g)
        s = b >> 5; int t = b & 31;
        kt = t >> 3; g = t & 7;
        ksteps = 8;
        src = W1 + (size_t)s * EEG * CLIP;
        dstbase = w1p + (size_t)s * CLIP * EEG;
    } else {                           // W2: 13 x (8 kt)x(8 g)
        b -= 416; s = b >> 6; int t = b & 63;
        kt = t >> 3; g = t & 7;
        ksteps = 16;
        src = W2 + (size_t)s * CLIP * CLIP;
        dstbase = w2p + (size_t)s * CLIP * CLIP;
    }
    int k0 = kt << 6, n0 = g << 6;
    int tid = threadIdx.x;
    int rk = tid >> 2;
    int cg = (tid & 3) << 4;
    const float4* p4 = reinterpret_cast<const float4*>(src + (size_t)(k0 + rk) * CLIP + n0 + cg);
    #pragma unroll
    for (int jj = 0; jj < 4; ++jj) {
        float4 v = p4[jj];
        T[cg + jj * 4 + 0][rk] = f2bf(v.x);
        T[cg + jj * 4 + 1][rk] = f2bf(v.y);
        T[cg + jj * 4 + 2][rk] = f2bf(v.z);
        T[cg + jj * 4 + 3][rk] = f2bf(v.w);
    }
    __syncthreads();
    int colin = tid & 63, sl = (tid >> 6) & 3;
    #pragma unroll
    for (int half = 0; half < 2; ++half) {
        int t = kt * 2 + half;
        u16* dst = dstbase + ((size_t)(g * ksteps + t)) * 2048 + sl * 512 + colin * 8;
        *reinterpret_cast<short8*>(dst) =
            *reinterpret_cast<const short8*>(&T[colin][half * 32 + sl * 8]);
    }
    if (blockIdx.x < 64) {             // fused histogram
        if (tid < NSUB) hh[tid] = 0;
        __syncthreads();
        atomicAdd(&hh[sid[blockIdx.x * 256 + tid]], 1);
        __syncthreads();
        if (tid < NSUB) meta[M_BCNT + blockIdx.x * NSUB + tid] = hh[tid];
    }
}

// ---- scan + scatter in one kernel ----
__global__ __launch_bounds__(256) void scanscatter_k(
    const int* __restrict__ sid, int* __restrict__ meta) {
    __shared__ int cnt[64][NSUB];
    __shared__ int so[NSUB + 1], myoff[NSUB], tot[NSUB];
    __shared__ int h[NSUB];
    int tid = threadIdx.x;
    for (int i = tid; i < 64 * NSUB; i += 256)
        cnt[i / NSUB][i % NSUB] = meta[M_BCNT + i];
    if (tid < NSUB) h[tid] = 0;
    __syncthreads();
    if (tid < NSUB) {
        int run = 0, mine = 0;
        for (int b = 0; b < 64; ++b) {
            if (b == (int)blockIdx.x) mine = run;
            run += cnt[b][tid];
        }
        tot[tid] = run; myoff[tid] = mine;
    }
    __syncthreads();
    if (tid == 0) {
        int off = 0;
        for (int s = 0; s < NSUB; ++s) { so[s] = off; off += tot[s]; }
        so[NSUB] = off;
    }
    __syncthreads();
    if (blockIdx.x == 0) {
        if (tid < NSUB + 1) meta[M_SOFF + tid] = so[tid];
        if (tid < NSUB) meta[M_TOT + tid] = tot[tid];
        if (tid == 0) {
            int c128 = 0;
            for (int s = 0; s < NSUB; ++s) {
                meta[M_C128 + s] = c128;
                c128 += (tot[s] + 127) >> 7;
            }
            meta[M_C128 + NSUB] = c128;
        }
    }
    int i = blockIdx.x * 256 + tid;
    int s = sid[i];
    int r = atomicAdd(&h[s], 1);
    meta[M_IDX + so[s] + myoff[s] + r] = i;
}

// ---- fused MLP: M=128 rows, full pipeline in one block ----
__global__ __launch_bounds__(1024) void mlp_k(
    const float* __restrict__ X, const float* __restrict__ b1,
    const float* __restrict__ b2, const u16* __restrict__ w1p,
    const u16* __restrict__ w2p, const int* __restrict__ meta,
    float* __restrict__ out) {

    __shared__ u16 Hs[128 * 520];      // 133.1 KB; head doubles as Xc[128][72]
    __shared__ float partial[128 * 8]; // 4 KB
    __shared__ float scalev[128];
    __shared__ int info[4];
    __shared__ int rowidx[128];
    __shared__ int cobuf[14], sobuf[14], totbuf[NSUB];

    int tid = threadIdx.x;

    // bijective XCD swizzle (m204)
    int nwg = gridDim.x;
    int q = nwg >> 3, r = nwg & 7;
    int xcd = blockIdx.x & 7, idx = blockIdx.x >> 3;
    int bid = (xcd < r) ? xcd * (q + 1) + idx : r * (q + 1) + (xcd - r) * q + idx;

    if (tid < 14) { cobuf[tid] = meta[M_C128 + tid]; sobuf[tid] = meta[M_SOFF + tid]; }
    if (tid < NSUB) totbuf[tid] = meta[M_TOT + tid];
    __syncthreads();
    if (tid == 0) {
        int total = cobuf[NSUB];
        if (bid < total) {
            int s = 0;
            while (s < NSUB && !(bid >= cobuf[s] && bid < cobuf[s + 1])) s++;
            int chunk = bid - cobuf[s];
            info[0] = s;
            info[1] = sobuf[s] + chunk * 128;
            info[2] = min(128, totbuf[s] - chunk * 128);
        } else info[0] = -1;
    }
    __syncthreads();
    if (info[0] < 0) return;
    int s = info[0], rowbase = info[1], nrows = info[2];
    if (tid < 128) rowidx[tid] = meta[M_IDX + rowbase + min(tid, nrows - 1)];

    int wave = tid >> 6, lane = tid & 63;
    int c = lane & 15, gl = lane >> 4;
    int wm = wave >> 3, wn = wave & 7;     // 2M x 8N
    int col0 = wn * 64;                    // this wave's 64 cols (both layers)
    const u16* w1c = w1p + (size_t)s * CLIP * EEG + (size_t)wn * 8 * 2048;
    const u16* w2c = w2p + (size_t)s * CLIP * CLIP + (size_t)wn * 16 * 2048;

    u16* Xc = Hs;                          // alias; temporally separated

    // ---- layer 1: H = relu(X @ W1 + b1), X staged in 64-wide K-chunks ----
    f32x4 acc[4][4];
    #pragma unroll
    for (int mi = 0; mi < 4; ++mi)
        #pragma unroll
        for (int ni = 0; ni < 4; ++ni)
            acc[mi][ni] = (f32x4){0.f, 0.f, 0.f, 0.f};

    int srow = tid >> 3, sl8 = tid & 7;    // 128 rows, 8 thr/row, 2 float4 each

    for (int kc = 0; kc < 4; ++kc) {
        __syncthreads();
        {
            const float4* xp = reinterpret_cast<const float4*>(
                X + (size_t)rowidx[srow] * EEG) + kc * 16;
            u16* xd = &Xc[srow * 72];
            #pragma unroll
            for (int half = 0; half < 2; ++half) {
                int j = sl8 + half * 8;
                float4 v = xp[j];
                union { u16 u[4]; uint2 qq; } pk;
                pk.u[0] = f2bf(v.x); pk.u[1] = f2bf(v.y);
                pk.u[2] = f2bf(v.z); pk.u[3] = f2bf(v.w);
                *reinterpret_cast<uint2*>(&xd[j * 4]) = pk.qq;
            }
        }
        __syncthreads();
        #pragma unroll
        for (int k0 = 0; k0 < 64; k0 += 32) {
            int t = kc * 2 + (k0 >> 5);
            short8 a[4], bb[4];
            #pragma unroll
            for (int ni = 0; ni < 4; ++ni)
                bb[ni] = *reinterpret_cast<const short8*>(
                    &w1c[(size_t)t * 2048 + gl * 512 + (ni * 16 + c) * 8]);
            #pragma unroll
            for (int mi = 0; mi < 4; ++mi)
                a[mi] = *reinterpret_cast<const short8*>(
                    &Xc[(wm * 64 + mi * 16 + c) * 72 + k0 + gl * 8]);
            #pragma unroll
            for (int mi = 0; mi < 4; ++mi)
                #pragma unroll
                for (int ni = 0; ni < 4; ++ni)
                    acc[mi][ni] = __builtin_amdgcn_mfma_f32_16x16x32_bf16(a[mi], bb[ni], acc[mi][ni], 0, 0, 0);
        }
    }
    __syncthreads();   // all waves done reading Xc (head of Hs)

    // bias + relu -> Hs (stride 520)
    {
        float bias1[4];
        #pragma unroll
        for (int ni = 0; ni < 4; ++ni) bias1[ni] = b1[s * CLIP + col0 + ni * 16 + c];
        #pragma unroll
        for (int mi = 0; mi < 4; ++mi)
            #pragma unroll
            for (int ni = 0; ni < 4; ++ni)
                #pragma unroll
                for (int i = 0; i < 4; ++i) {
                    float h = fmaxf(acc[mi][ni][i] + bias1[ni], 0.f);
                    Hs[(wm * 64 + mi * 16 + gl * 4 + i) * 520 + col0 + ni * 16 + c] = f2bf(h);
                }
    }
    __syncthreads();

    // ---- layer 2: Y = H @ W2 + b2 (barrier-free k-loop) ----
    #pragma unroll
    for (int mi = 0; mi < 4; ++mi)
        #pragma unroll
        for (int ni = 0; ni < 4; ++ni)
            acc[mi][ni] = (f32x4){0.f, 0.f, 0.f, 0.f};

    #pragma unroll 4
    for (int k0 = 0; k0 < CLIP; k0 += 32) {
        int t = k0 >> 5;
        short8 a[4], bb[4];
        #pragma unroll
        for (int ni = 0; ni < 4; ++ni)
            bb[ni] = *reinterpret_cast<const short8*>(
                &w2c[(size_t)t * 2048 + gl * 512 + (ni * 16 + c) * 8]);
        #pragma unroll
        for (int mi = 0; mi < 4; ++mi)
            a[mi] = *reinterpret_cast<const short8*>(
                &Hs[(wm * 64 + mi * 16 + c) * 520 + k0 + gl * 8]);
        #pragma unroll
        for (int mi = 0; mi < 4; ++mi)
            #pragma unroll
            for (int ni = 0; ni < 4; ++ni)
                acc[mi][ni] = __builtin_amdgcn_mfma_f32_16x16x32_bf16(a[mi], bb[ni], acc[mi][ni], 0, 0, 0);
    }

    // bias + squared row-sums (this wave's 64 cols of its 64 rows)
    float sq[4][4];
    {
        float bias2[4];
        #pragma unroll
        for (int ni = 0; ni < 4; ++ni) bias2[ni] = b2[s * CLIP + col0 + ni * 16 + c];
        #pragma unroll
        for (int mi = 0; mi < 4; ++mi)
            #pragma unroll
            for (int i = 0; i < 4; ++i) sq[mi][i] = 0.f;
        #pragma unroll
        for (int mi = 0; mi < 4; ++mi)
            #pragma unroll
            for (int ni = 0; ni < 4; ++ni)
                #pragma unroll
                for (int i = 0; i < 4; ++i) {
                    float v = acc[mi][ni][i] + bias2[ni];
                    acc[mi][ni][i] = v;
                    sq[mi][i] += v * v;
                }
    }
    #pragma unroll
    for (int m = 1; m < 16; m <<= 1)
        #pragma unroll
        for (int mi = 0; mi < 4; ++mi)
            #pragma unroll
            for (int i = 0; i < 4; ++i)
                sq[mi][i] += __shfl_xor(sq[mi][i], m);

    if (c == 0) {
        #pragma unroll
        for (int mi = 0; mi < 4; ++mi)
            #pragma unroll
            for (int i = 0; i < 4; ++i)
                partial[(wm * 64 + mi * 16 + gl * 4 + i) * 8 + wn] = sq[mi][i];
    }
    __syncthreads();
    if (tid < 128) {
        float t = 0.f;
        #pragma unroll
        for (int w = 0; w < 8; ++w) t += partial[tid * 8 + w];
        scalev[tid] = 1.f / fmaxf(sqrtf(t), 1e-12f);
    }
    __syncthreads();

    #pragma unroll
    for (int mi = 0; mi < 4; ++mi)
        #pragma unroll
        for (int i = 0; i < 4; ++i) {
            int row = wm * 64 + mi * 16 + gl * 4 + i;
            if (row < nrows) {
                float sc = scalev[row];
                float* op = out + (size_t)rowidx[row] * CLIP + col0 + c;
                #pragma unroll
                for (int ni = 0; ni < 4; ++ni)
                    __builtin_nontemporal_store(acc[mi][ni][i] * sc, op + ni * 16);
            }
        }
}

extern "C" void kernel_launch(void* const* d_in, const int* in_sizes, int n_in,
                              void* d_out, int out_size, void* d_ws, size_t ws_size,
                              hipStream_t stream) {
    const float* eeg = (const float*)d_in[0];
    const int* sid   = (const int*)d_in[1];
    const float* W1  = (const float*)d_in[2];
    const float* b1  = (const float*)d_in[3];
    const float* W2  = (const float*)d_in[4];
    const float* b2  = (const float*)d_in[5];
    float* out = (float*)d_out;

    u16* w1p = (u16*)d_ws;                                   // 3.4 MB (packed)
    u16* w2p = w1p + (size_t)NSUB * CLIP * EEG;              // 6.8 MB (packed)
    int* meta = (int*)(w2p + (size_t)NSUB * CLIP * CLIP);    // ~68 KB

    convert_pack<<<1248, 256, 0, stream>>>(W1, W2, w1p, w2p, sid, meta);
    scanscatter_k<<<64, 256, 0, stream>>>(sid, meta);
    mlp_k<<<BATCH / 128 + NSUB, 1024, 0, stream>>>(eeg, b1, b2, w1p, w2p, meta, out);
}